// Round 9
// baseline (2284.070 us; speedup 1.0000x reference)
//
#include <hip/hip_runtime.h>
#include <stdint.h>

// SPINN thin-stack TreeLSTM, MI355X, round 15: r10 overlap + r14 drain.
// Mechanism reconciliation of r8/r10/r14: r8/r14's in-P2 poll works BECAUSE
// __syncthreads' vmcnt(0) drain forces the ring publish to L2 each phase;
// r10's early-poll failed because its lgkmcnt-only barrier let the publish
// linger in the store queue. This round: poll at P1 start (waves 6-7 only,
// self-gated, hidden under waves 0-5 GEMM) targeting h(t-1) that the
// P2(t-1)-end __syncthreads ALREADY drained to L2 -> first-try hit.
// P2 has no poll: cell + prefetch + drain only.
// Pair = (bid, bid^8) same-XCD (r14-verified). Cell + GEMM bodies = r8
// verified. Poll backoff: 4 sleepless tries then s_sleep(1).
// xs K-layout (block-local): [0,64) label | [64,128) hl-own | [128,192)
// hl-partner | [192,256) hr-own | [256,320) hr-partner.

#define D     512
#define HD    128
#define LD    64
#define NTHR  512
#define GPR   328   // gp row stride (floats): 256 quad cols + 64 u cols + pad

typedef unsigned long long u64t;

__device__ __forceinline__ float sigf(float x){ return 1.0f/(1.0f+__expf(-x)); }
__device__ __forceinline__ float tanh_(float x){ return 1.0f-2.0f/(__expf(2.0f*x)+1.0f); }
__device__ __forceinline__ u64t gld64(const float* p){
  return __hip_atomic_load((const u64t*)p, __ATOMIC_RELAXED, __HIP_MEMORY_SCOPE_AGENT);
}
__device__ __forceinline__ u64t gld64r(const u64t* p){
  return __hip_atomic_load(p, __ATOMIC_RELAXED, __HIP_MEMORY_SCOPE_AGENT);
}
__device__ __forceinline__ void gst32(float* p, float v){
  __hip_atomic_store(p, v, __ATOMIC_RELAXED, __HIP_MEMORY_SCOPE_AGENT);
}
__device__ __forceinline__ void gst64r(u64t* p, u64t v){
  __hip_atomic_store(p, v, __ATOMIC_RELAXED, __HIP_MEMORY_SCOPE_AGENT);
}
__device__ __forceinline__ u64t packw(float v, unsigned tg){
  return ((u64t)tg << 32) | (u64t)__float_as_uint(v);
}
__device__ __forceinline__ float loww(u64t w){
  return __uint_as_float((unsigned)(w & 0xffffffffu));
}
__device__ __forceinline__ int permrow(int k, int sl){
  // block-local k -> global W row (xs layout in header)
  const int ps = sl^1;
  if (k < 64)  return k;
  if (k < 128) return 64  + sl*64 + (k-64);
  if (k < 192) return 64  + ps*64 + (k-128);
  if (k < 256) return 192 + sl*64 + (k-192);
  return 192 + ps*64 + (k-256);
}

__global__ __launch_bounds__(NTHR,2) void spinn_kernel(
    const int* __restrict__ trans, const int* __restrict__ labels,
    const float* __restrict__ emb, const float* __restrict__ W,
    const float* __restrict__ bias, const float* __restrict__ leaf,
    float* __restrict__ out, u64t* __restrict__ ring,
    float* __restrict__ rec, float* __restrict__ cown)
{
  const int bid = blockIdx.x;
  // SAME-XCD pair: (bid, bid^8). XCD(bid)=bid%8 -> both blocks one XCD.
  const int g2 = ((bid>>4)<<3) | (bid&7);   // bijective pair index [0,128)
  const int sl = (bid>>3)&1, ps = sl^1;
  const int gb0 = g2*2;
  const int tid = threadIdx.x;
  const int kg = tid>>6, lane = tid&63;
  const int cq = lane;

  __shared__ __align__(16) float xs[2][2][320];     // [buf][b][k] (permuted K)
  __shared__ __align__(16) float gpq[16][GPR];      // [(kg*2+b)][col]
  __shared__ float bsl[320];
  __shared__ float lshd[HD];
  __shared__ float clb[2][2][64];
  __shared__ uint8_t mS[D][2];
  __shared__ short liA[D][2];
  __shared__ unsigned short stk_[2][D];

  // --- W slice into registers: 40 permuted K-rows x (4 quad cols + 1 u col) ---
  float4 wr4[40]; float wr1[40];
  {
    const int gq = (cq>>4)*128 + sl*64 + ((cq*4)&63);  // quad base (gates 0-3)
    const int gu = 512 + sl*64 + cq;                   // u-gate col
#pragma unroll
    for (int j=0;j<40;++j){
      const int R = permrow(kg*40 + j, sl);
      wr4[j] = *(const float4*)(W + (size_t)R*640 + gq);
      wr1[j] = W[(size_t)R*640 + gu];
    }
  }
  if (tid < 320){
    int c = tid;
    int gc = (c < 256) ? ((c>>6)*128 + sl*64 + (c&63)) : (512 + sl*64 + (c-256));
    bsl[c] = bias[gc];
  }
  if (tid < HD) lshd[tid] = leaf[tid];
  if (tid < 2){   // precompute (mask, li); ri == t-1 always on a reduce
    int b = tid, p = 0;
    for (int t=0;t<D;++t){
      int m = trans[t*256 + gb0 + b];
      short li = 0;
      if (m) li = (short)stk_[b][p-2];
      mS[t][b] = (uint8_t)m; liA[t][b] = li;
      int np = p - 2*m; stk_[b][np] = (unsigned short)t; p = np+1;
    }
  }
  __syncthreads();

  // --- prefill xs[0] (mask(0)==0 by construction): label + leaf halves ---
  for (int idx = tid; idx < 640; idx += NTHR){
    const int b = (idx >= 320) ? 1 : 0;
    const int r = idx - b*320;
    float v;
    if (r < 64)       v = emb[(size_t)labels[gb0 + b]*LD + r];
    else if (r < 128) v = lshd[sl*64 + (r-64)];
    else if (r < 192) v = lshd[ps*64 + (r-128)];
    else if (r < 256) v = lshd[sl*64 + (r-192)];
    else              v = lshd[ps*64 + (r-256)];
    xs[0][b][r] = v;
  }
  __syncthreads();

  // GEMM over j4 groups [j0,j1) of this wave's 40 K-rows (r8-verified body)
  auto gemmr = [&](int cur, int j0, int j1,
                   float4& a0, float4& a1, float& u0, float& u1){
#pragma unroll
    for (int j4=j0;j4<j1;++j4){
      int k = kg*40 + j4*4;
      float4 x0 = *(const float4*)&xs[cur][0][k];   // broadcast (all lanes same)
      float4 x1 = *(const float4*)&xs[cur][1][k];
      float xa0[4] = {x0.x,x0.y,x0.z,x0.w};
      float xa1[4] = {x1.x,x1.y,x1.z,x1.w};
#pragma unroll
      for (int jj=0;jj<4;++jj){
        float4 w = wr4[j4*4+jj];
        float wu = wr1[j4*4+jj];
        a0.x = __builtin_fmaf(w.x, xa0[jj], a0.x);
        a0.y = __builtin_fmaf(w.y, xa0[jj], a0.y);
        a0.z = __builtin_fmaf(w.z, xa0[jj], a0.z);
        a0.w = __builtin_fmaf(w.w, xa0[jj], a0.w);
        a1.x = __builtin_fmaf(w.x, xa1[jj], a1.x);
        a1.y = __builtin_fmaf(w.y, xa1[jj], a1.y);
        a1.z = __builtin_fmaf(w.z, xa1[jj], a1.z);
        a1.w = __builtin_fmaf(w.w, xa1[jj], a1.w);
        u0 = __builtin_fmaf(wu, xa0[jj], u0);
        u1 = __builtin_fmaf(wu, xa1[jj], u1);
      }
    }
  };

  float ccprev = 0.f;   // own c[t-1][b][dl] (cell threads only)

  for (int t=0;t<D;++t){
    const int cur = t&1, nxt = cur^1;

    // ===== P1: GEMM; waves 6,7 first-try-poll partner h(t-1) (drained) =====
    {
      float4 a0 = {0.f,0.f,0.f,0.f}, a1 = {0.f,0.f,0.f,0.f};
      float u0 = 0.f, u1 = 0.f;

      if (kg <= 5){
        gemmr(cur, 0, 10, a0, a1, u0, u1);          // k < 240: no dependency
      } else if (kg == 6){
        gemmr(cur, 0, 4, a0, a1, u0, u1);           // k 240..255 (own-hr)
        if (t > 0){                                 // poll dl 0..23, b=0,1
          const size_t rb = ((((size_t)((t-1)&7))*128 + g2)*2 + ps)*128;
          const unsigned want = (unsigned)t;        // tag = (t-1)+1
          const bool act = (lane < 24) || (lane >= 32 && lane < 56);
          const int b = lane >> 5;
          const int dl = act ? (b ? lane-32 : lane) : 0;
          const u64t* rp = ring + rb + b*64 + dl;
          u64t w0 = ((u64t)want)<<32; int it = 0;
          for (;;){
            if (act) w0 = gld64r(rp);
            if (__all((unsigned)(w0>>32) == want)) break;
            if (it >= 4) __builtin_amdgcn_s_sleep(1);
            if (++it > (1<<20)) break;              // safety: hang -> wrong
          }
          if (act)
            xs[cur][b][256+dl] = mS[t][b] ? loww(w0) : lshd[ps*64+dl];
        }
        gemmr(cur, 4, 10, a0, a1, u0, u1);          // k 256..279 (partner-hr)
      } else { // kg == 7
        if (t > 0){                                 // poll dl 24..63, b=0,1
          const size_t rb = ((((size_t)((t-1)&7))*128 + g2)*2 + ps)*128;
          const unsigned want = (unsigned)t;
          const bool act = (lane < 40);
          const int dl = 24 + (act ? lane : 0);
          const u64t* rp0 = ring + rb + dl;         // b = 0
          const u64t* rp1 = ring + rb + 64 + dl;    // b = 1
          u64t w0 = ((u64t)want)<<32, w1 = w0; int it = 0;
          for (;;){
            if (act){ w0 = gld64r(rp0); w1 = gld64r(rp1); }
            if (__all(((unsigned)(w0>>32) == want) &
                      ((unsigned)(w1>>32) == want))) break;
            if (it >= 4) __builtin_amdgcn_s_sleep(1);
            if (++it > (1<<20)) break;
          }
          if (act){
            xs[cur][0][256+dl] = mS[t][0] ? loww(w0) : lshd[ps*64+dl];
            xs[cur][1][256+dl] = mS[t][1] ? loww(w1) : lshd[ps*64+dl];
          }
        }
        gemmr(cur, 0, 10, a0, a1, u0, u1);          // k 280..319 (own deposit)
      }
      *(float4*)&gpq[kg*2+0][cq*4] = a0;
      *(float4*)&gpq[kg*2+1][cq*4] = a1;
      gpq[kg*2+0][256+cq] = u0;
      gpq[kg*2+1][256+cq] = u1;
    }
    __syncthreads();   // full drain: keeps publish pipeline tight (r14 lesson)

    // ===== P2: cell (w0-1) || prefetch t+1 (w2-4); NO poll here ============
    if (tid < 128){
      const int b = tid>>6, dl = tid&63, gd = sl*64+dl;
      const int m = mS[t][b];
      float s[5];
#pragma unroll
      for (int g=0; g<5; ++g){
        int c = (g<4) ? (g*64+dl) : (256+dl);
        float a = 0.f;
#pragma unroll
        for (int kk=0; kk<8; ++kk) a += gpq[kk*2+b][c];
        s[g] = a + bsl[c];
      }
      const float cl_ = m ? clb[cur][b][dl] : lshd[gd];
      const float cr_ = m ? ccprev : lshd[gd];      // ri == t-1: own prev c
      const float cc = sigf(s[0])*tanh_(s[4]) + sigf(s[1])*cl_ + sigf(s[2])*cr_;
      const float hh = sigf(s[3])*tanh_(cc);
      ccprev = cc;
      // publish self-tagged h FIRST; P2-end __syncthreads drains it to L2,
      // so partner's P1(t+1) poll hits first try.
      gst64r(ring + (((size_t)(t&7)*128 + g2)*2 + sl)*128 + tid,
             packw(hh, (unsigned)(t+1)));
      const size_t ro = (((size_t)t*128 + g2)*2 + sl)*128 + b*64 + dl;
      gst32(rec + ro, hh);
      gst32(cown + ro, cc);
      if (t == D-1){
        out[(size_t)(gb0+b)*HD + gd] = cc;
        out[(size_t)256*HD + (size_t)(gb0+b)*HD + gd] = hh;
      } else {
        xs[nxt][b][192+dl] = mS[t+1][b] ? hh : lshd[gd];   // own hr for t+1
      }
      if (t+2 < D && mS[t+2][b] && liA[t+2][b] == t){
        xs[cur][b][64+dl] = hh;     // own hl for t+2 (li==t case)
        clb[cur][b][dl]   = cc;     // own cl for t+2
      }
    } else if (kg == 2){            // emb(t+1) -> label slots
      if (t+1 < D){
        const int b = lane>>5, jj = lane&31;
        const int row = labels[(t+1)*256 + gb0 + b];
        const float2 ev = *(const float2*)(emb + (size_t)row*LD + jj*2);
        xs[nxt][b][jj*2]   = ev.x;
        xs[nxt][b][jj*2+1] = ev.y;
      }
    } else if (kg == 3){            // own-half hl/cl for t+1
      if (t+1 < D){
        const int b = lane>>5, jj = lane&31;
        const int m1 = mS[t+1][b]; const int li = liA[t+1][b];
        if (m1){
          if (li <= t-2){
            const size_t ro = (((size_t)li*128+g2)*2 + sl)*128 + b*64 + jj*2;
            union{u64t u; float f[2];} h_, c_;
            h_.u = gld64(rec + ro);
            c_.u = gld64(cown + ro);
            xs[nxt][b][64+jj*2]   = h_.f[0];
            xs[nxt][b][64+jj*2+1] = h_.f[1];
            clb[nxt][b][jj*2]     = c_.f[0];
            clb[nxt][b][jj*2+1]   = c_.f[1];
          }
          // li == t-1: cell@t-1 already wrote xs/clb from registers
        } else {
          xs[nxt][b][64+jj*2]   = lshd[sl*64+jj*2];
          xs[nxt][b][64+jj*2+1] = lshd[sl*64+jj*2+1];
          clb[nxt][b][jj*2]     = lshd[sl*64+jj*2];
          clb[nxt][b][jj*2+1]   = lshd[sl*64+jj*2+1];
        }
      }
    } else if (kg == 4){            // partner-half hl for t+1
      if (t+1 < D){
        const int b = lane>>5, jj = lane&31;
        const int m1 = mS[t+1][b]; const int li = liA[t+1][b];
        if (m1){
          if (li <= t-2){
            const size_t ro = (((size_t)li*128+g2)*2 + ps)*128 + b*64 + jj*2;
            union{u64t u; float f[2];} h_;
            h_.u = gld64(rec + ro);
            xs[nxt][b][128+jj*2]   = h_.f[0];
            xs[nxt][b][128+jj*2+1] = h_.f[1];
          } else {                  // li == t-1: slot verified by P1(t) polls
            const u64t* rp = ring + (((size_t)((t-1)&7)*128 + g2)*2 + ps)*128
                             + b*64 + jj*2;
            xs[nxt][b][128+jj*2]   = loww(gld64r(rp));
            xs[nxt][b][128+jj*2+1] = loww(gld64r(rp+1));
          }
        } else {
          xs[nxt][b][128+jj*2]   = lshd[ps*64+jj*2];
          xs[nxt][b][128+jj*2+1] = lshd[ps*64+jj*2+1];
        }
      }
    }
    __syncthreads();   // full drain: forces ring publish to L2 before P1(t+1)
  }
}

extern "C" void kernel_launch(void* const* d_in, const int* in_sizes, int n_in,
                              void* d_out, int out_size, void* d_ws, size_t ws_size,
                              hipStream_t stream) {
  (void)in_sizes; (void)n_in; (void)out_size; (void)ws_size;
  const int*   trans  = (const int*)d_in[0];
  const int*   labels = (const int*)d_in[1];
  const float* emb    = (const float*)d_in[2];
  const float* W      = (const float*)d_in[3];
  const float* bias   = (const float*)d_in[4];
  const float* leaf   = (const float*)d_in[5];
  float* out = (float*)d_out;

  // ws: [0, 2MB)   ring: 8-deep self-tagged h records, u64 per (slot,g2,sl,b,dl)
  //               (tag = t+1: 0xAA poison AND zero-init != any live tag;
  //                slot reuse distance 8 steps, pair skew <=1 step -> safe)
  //     [8MB,72MB)  rec:  plain h records (li<=t-2 readers, >=2 steps old)
  //     [72MB,136MB) cown: plain c records (own-block readers only)
  uint8_t* ws = (uint8_t*)d_ws;
  u64t*  ring = (u64t*)ws;
  float* rec  = (float*)(ws + ((size_t)8<<20));
  float* cown = (float*)(ws + ((size_t)72<<20));

  spinn_kernel<<<dim3(256), dim3(NTHR), 0, stream>>>(
      trans, labels, emb, W, bias, leaf, out, ring, rec, cown);
}

// Round 11
// 1710.196 us; speedup vs baseline: 1.3356x; 1.3356x over previous
//
#include <hip/hip_runtime.h>
#include <stdint.h>

// SPINN thin-stack TreeLSTM, MI355X, round 17: r16 gate-sum shipping,
// resubmitted after infra failure ("container failed twice", no test output).
// Audit found no deadlock/OOB; only hardening change: poll cap 1<<20 -> 1<<17
// so any pathological spin ends in a wrong answer, never a watchdog timeout.
// Scheme: pair (bid, bid^8) same-XCD. Block sl owns 320 gate cols; GEMM
// byte-identical r8/r14. After P1 barrier each block reduces its gpq into 640
// raw sums and ships them as tagged u64s (4-deep mailbox). Each block then
// runs the FULL 128-dim cell for both batch elems (duplicate transcendentals):
// own-half gates = r8 inline gpq reduce; partner-half = 5 tagged mailbox
// loads (waves partition cleanly; __all is wave-uniform). h/c state is fully
// block-local: NO ring, NO wave-7 poll, NO partner-hl prefetch. rec/cown
// pair-shared, single writer (sl==0); reader safety: mutual mailbox
// dependency bounds pair skew <=1 phase, and each block's __syncthreads
// drains its stores to L2 before the mailbox tag that the reader observed.

#define D     512
#define HD    128
#define LD    64
#define NTHR  512
#define GPR   328   // gpq row stride (floats): 256 quad cols + 64 u cols + pad

typedef unsigned long long u64t;

__device__ __forceinline__ float sigf(float x){ return 1.0f/(1.0f+__expf(-x)); }
__device__ __forceinline__ float tanh_(float x){ return 1.0f-2.0f/(__expf(2.0f*x)+1.0f); }
__device__ __forceinline__ u64t gld64(const float* p){
  return __hip_atomic_load((const u64t*)p, __ATOMIC_RELAXED, __HIP_MEMORY_SCOPE_AGENT);
}
__device__ __forceinline__ u64t gld64r(const u64t* p){
  return __hip_atomic_load(p, __ATOMIC_RELAXED, __HIP_MEMORY_SCOPE_AGENT);
}
__device__ __forceinline__ void gst32(float* p, float v){
  __hip_atomic_store(p, v, __ATOMIC_RELAXED, __HIP_MEMORY_SCOPE_AGENT);
}
__device__ __forceinline__ void gst64r(u64t* p, u64t v){
  __hip_atomic_store(p, v, __ATOMIC_RELAXED, __HIP_MEMORY_SCOPE_AGENT);
}
__device__ __forceinline__ u64t packw(float v, unsigned tg){
  return ((u64t)tg << 32) | (u64t)__float_as_uint(v);
}
__device__ __forceinline__ float loww(u64t w){
  return __uint_as_float((unsigned)(w & 0xffffffffu));
}

__global__ __launch_bounds__(NTHR,2) void spinn_kernel(
    const int* __restrict__ trans, const int* __restrict__ labels,
    const float* __restrict__ emb, const float* __restrict__ W,
    const float* __restrict__ bias, const float* __restrict__ leaf,
    float* __restrict__ out, u64t* __restrict__ mail,
    float* __restrict__ rec, float* __restrict__ cown)
{
  const int bid = blockIdx.x;
  // SAME-XCD pair: (bid, bid^8); bijective pair index (r14-verified).
  const int g2 = ((bid>>4)<<3) | (bid&7);
  const int sl = (bid>>3)&1, ps = sl^1;
  const int gb0 = g2*2;
  const int tid = threadIdx.x;
  const int kg = tid>>6, lane = tid&63;
  const int cq = lane;

  __shared__ __align__(16) float xs[2][2][320];  // [buf][b][k]: 64 lab|128 hl|128 hr (GLOBAL k)
  __shared__ __align__(16) float gpq[16][GPR];   // [(kg*2+b)][col] (own 320 cols)
  __shared__ float bsl[640];                     // bias, GLOBAL col index
  __shared__ float lshd[HD];
  __shared__ float clb[2][2][HD];                // full 128-dim cl buffer
  __shared__ uint8_t mS[D][2];
  __shared__ short liA[D][2];
  __shared__ unsigned short stk_[2][D];

  // --- W slice into registers: 40 K-rows x (4 quad cols + 1 u col) ---
  // byte-identical to r8/r14 (verified 128-VGPR codegen, FETCH-clean)
  float4 wr4[40]; float wr1[40];
  {
    const int gq = (cq>>4)*128 + sl*64 + ((cq*4)&63);
    const int gu = 512 + sl*64 + cq;
#pragma unroll
    for (int j=0;j<40;++j){
      int k = kg*40 + j;
      wr4[j] = *(const float4*)(W + (size_t)k*640 + gq);
      wr1[j] = W[(size_t)k*640 + gu];
    }
  }
  for (int c = tid; c < 640; c += NTHR) bsl[c] = bias[c];
  if (tid < HD) lshd[tid] = leaf[tid];
  if (tid < 2){   // precompute (mask, li); ri == t-1 always on a reduce
    int b = tid, p = 0;
    for (int t=0;t<D;++t){
      int m = trans[t*256 + gb0 + b];
      short li = 0;
      if (m) li = (short)stk_[b][p-2];
      mS[t][b] = (uint8_t)m; liA[t][b] = li;
      int np = p - 2*m; stk_[b][np] = (unsigned short)t; p = np+1;
    }
  }
  __syncthreads();

  // --- prefill xs[0]: emb(labels[0]) + leaf (mask(0)==0 by construction) ---
  for (int idx = tid; idx < 640; idx += NTHR){
    int b = (idx >= 320) ? 1 : 0;
    int r = idx - b*320;
    if (r < 64){
      int row = labels[gb0 + b];
      xs[0][b][r] = emb[(size_t)row*LD + r];
    } else {
      xs[0][b][r] = lshd[(r-64)&127];
    }
  }
  __syncthreads();

  auto gemm = [&](int cur){
    float4 a0 = {0.f,0.f,0.f,0.f}, a1 = {0.f,0.f,0.f,0.f};
    float u0 = 0.f, u1 = 0.f;
#pragma unroll
    for (int j4=0;j4<10;++j4){
      int k = kg*40 + j4*4;
      float4 x0 = *(const float4*)&xs[cur][0][k];   // broadcast (all lanes same)
      float4 x1 = *(const float4*)&xs[cur][1][k];
      float xa0[4] = {x0.x,x0.y,x0.z,x0.w};
      float xa1[4] = {x1.x,x1.y,x1.z,x1.w};
#pragma unroll
      for (int jj=0;jj<4;++jj){
        float4 w = wr4[j4*4+jj];
        float wu = wr1[j4*4+jj];
        a0.x = __builtin_fmaf(w.x, xa0[jj], a0.x);
        a0.y = __builtin_fmaf(w.y, xa0[jj], a0.y);
        a0.z = __builtin_fmaf(w.z, xa0[jj], a0.z);
        a0.w = __builtin_fmaf(w.w, xa0[jj], a0.w);
        a1.x = __builtin_fmaf(w.x, xa1[jj], a1.x);
        a1.y = __builtin_fmaf(w.y, xa1[jj], a1.y);
        a1.z = __builtin_fmaf(w.z, xa1[jj], a1.z);
        a1.w = __builtin_fmaf(w.w, xa1[jj], a1.w);
        u0 = __builtin_fmaf(wu, xa0[jj], u0);
        u1 = __builtin_fmaf(wu, xa1[jj], u1);
      }
    }
    *(float4*)&gpq[kg*2+0][cq*4] = a0;
    *(float4*)&gpq[kg*2+1][cq*4] = a1;
    gpq[kg*2+0][256+cq] = u0;
    gpq[kg*2+1][256+cq] = u1;
  };

  float ccprev = 0.f;   // own c[t-1][b][h] (cell threads only, full-local)

  for (int t=0;t<D;++t){
    const int cur = t&1, nxt = cur^1;

    // ===== P1: ALL 8 waves GEMM full K=320; zero cross-block deps ==========
    gemm(cur);
    __syncthreads();

    // ===== P2: ship sums -> full-local cell -> local prefetch ==============
    // (1) every thread reduces + ships its word(s) of the 640 raw gate sums
    {
      u64t* mo = mail + (((size_t)(t&3)*128 + g2)*2 + sl)*640;
      {
        const int w = tid;                    // 0..511
        const int b = (w >= 320), c = w - b*320;
        float a = 0.f;
#pragma unroll
        for (int kk=0; kk<8; ++kk) a += gpq[kk*2+b][c];
        gst64r(mo + w, packw(a, (unsigned)(t+1)));
      }
      if (tid < 128){                         // words 512..639
        const int w = 512 + tid;
        const int c = w - 320;                // b=1, c=192..319
        float a = 0.f;
#pragma unroll
        for (int kk=0; kk<8; ++kk) a += gpq[kk*2+1][c];
        gst64r(mo + w, packw(a, (unsigned)(t+1)));
      }
    }

    // (2) full 128-dim cell on tid<256 (both halves, duplicated across pair)
    if (tid < 256){
      const int b = tid>>7, h = tid&127, dl = h&63;
      const int own = ((h>>6) == sl);
      const int m = mS[t][b];
      float s[5];
      if (own){
        // own-half gates: r8 inline reduce over own gpq
#pragma unroll
        for (int g=0; g<5; ++g){
          const int c = (g<4) ? (g*64+dl) : (256+dl);
          float a = 0.f;
#pragma unroll
          for (int kk=0; kk<8; ++kk) a += gpq[kk*2+b][c];
          s[g] = a;
        }
      } else {
        // partner-half gates: tagged mailbox (shipped at partner P2(t) start)
        const u64t* mi = mail + (((size_t)(t&3)*128 + g2)*2 + ps)*640 + b*320;
        const unsigned want = (unsigned)(t+1);
        u64t pw[5];
#pragma unroll
        for (int g=0;g<4;++g) pw[g] = gld64r(mi + g*64 + dl);
        pw[4] = gld64r(mi + 256 + dl);
        int it = 0;
        while (!__all(((unsigned)(pw[0]>>32) == want) &
                      ((unsigned)(pw[1]>>32) == want) &
                      ((unsigned)(pw[2]>>32) == want) &
                      ((unsigned)(pw[3]>>32) == want) &
                      ((unsigned)(pw[4]>>32) == want))){
          if (it >= 4) __builtin_amdgcn_s_sleep(1);
#pragma unroll
          for (int g=0;g<4;++g) pw[g] = gld64r(mi + g*64 + dl);
          pw[4] = gld64r(mi + 256 + dl);
          if (++it > (1<<17)) break;   // hardened cap: wrong answer, not hang
        }
#pragma unroll
        for (int g=0;g<5;++g) s[g] = loww(pw[g]);
      }
#pragma unroll
      for (int g=0;g<4;++g) s[g] += bsl[g*128 + h];
      s[4] += bsl[512 + h];

      const float cl_ = m ? clb[cur][b][h] : lshd[h];
      const float cr_ = m ? ccprev : lshd[h];     // ri == t-1: own prev c
      const float cc = sigf(s[0])*tanh_(s[4]) + sigf(s[1])*cl_ + sigf(s[2])*cr_;
      const float hh = sigf(s[3])*tanh_(cc);
      ccprev = cc;

      if (sl == 0){   // single writer; pair-shared records (values identical)
        const size_t ro = (((size_t)t*128 + g2)*2 + b)*HD + h;
        gst32(rec + ro, hh);
        gst32(cown + ro, cc);
      }
      if (t == D-1){
        out[(size_t)(gb0+b)*HD + h] = cc;          // duplicate same-value OK
        out[(size_t)256*HD + (size_t)(gb0+b)*HD + h] = hh;
      } else {
        xs[nxt][b][192+h] = mS[t+1][b] ? hh : lshd[h];   // hr for t+1 (full)
      }
      if (t+2 < D && mS[t+2][b] && liA[t+2][b] == t){
        xs[cur][b][64+h] = hh;    // hl for t+2 (li==t case, full)
        clb[cur][b][h]   = cc;    // cl for t+2
      }
    } else if (tid < 384){        // (3a) hl/cl for t+1 (local pair records)
      if (t+1 < D){
        const int idx = tid-256, b = idx>>6, jj = idx&63, h2 = jj*2;
        const int m1 = mS[t+1][b]; const int li = liA[t+1][b];
        if (m1){
          if (li <= t-2){
            const size_t ro = (((size_t)li*128 + g2)*2 + b)*HD + h2;
            union{u64t u; float f[2];} h_, c_;
            h_.u = gld64(rec + ro);
            c_.u = gld64(cown + ro);
            xs[nxt][b][64+h2]   = h_.f[0];
            xs[nxt][b][64+h2+1] = h_.f[1];
            clb[nxt][b][h2]     = c_.f[0];
            clb[nxt][b][h2+1]   = c_.f[1];
          }
          // li == t-1: cell@t-1 already wrote xs/clb from registers
        } else {
          xs[nxt][b][64+h2]   = lshd[h2];
          xs[nxt][b][64+h2+1] = lshd[h2+1];
          clb[nxt][b][h2]     = lshd[h2];
          clb[nxt][b][h2+1]   = lshd[h2+1];
        }
      }
    } else {                      // (3b) emb(t+1) -> label slots
      if (t+1 < D){
        const int idx = tid-384, b = idx>>6, jj = idx&63;
        const int row = labels[(t+1)*256 + gb0 + b];
        xs[nxt][b][jj] = emb[(size_t)row*LD + jj];
      }
    }
    __syncthreads();
  }
}

extern "C" void kernel_launch(void* const* d_in, const int* in_sizes, int n_in,
                              void* d_out, int out_size, void* d_ws, size_t ws_size,
                              hipStream_t stream) {
  (void)in_sizes; (void)n_in; (void)out_size; (void)ws_size;
  const int*   trans  = (const int*)d_in[0];
  const int*   labels = (const int*)d_in[1];
  const float* emb    = (const float*)d_in[2];
  const float* W      = (const float*)d_in[3];
  const float* bias   = (const float*)d_in[4];
  const float* leaf   = (const float*)d_in[5];
  float* out = (float*)d_out;

  // ws: [0, 6MiB)   mail: 4-deep tagged gate-sum words, 4 x 128 x 2 x 640 u64
  //                (tag = t+1: 0xAA poison AND zero-init never match; slot
  //                 reuse distance 4 steps, mutual dependency bounds pair
  //                 skew <=1 step -> safe)
  //     [8,72)MiB   rec:  pair-shared full h records (writer: sl==0 block;
  //                       readers >=2 steps behind, skew-safe per mailbox)
  //     [72,136)MiB cown: pair-shared full c records (same discipline)
  uint8_t* ws = (uint8_t*)d_ws;
  u64t*  mail = (u64t*)ws;
  float* rec  = (float*)(ws + ((size_t)8<<20));
  float* cown = (float*)(ws + ((size_t)72<<20));

  spinn_kernel<<<dim3(256), dim3(NTHR), 0, stream>>>(
      trans, labels, emb, W, bias, leaf, out, mail, rec, cown);
}